// Round 20
// baseline (97.923 us; speedup 1.0000x reference)
//
#include <hip/hip_runtime.h>
#include <stdint.h>

typedef unsigned short u16;
typedef unsigned char u8;
typedef __attribute__((ext_vector_type(8))) short short8;
typedef __attribute__((ext_vector_type(4))) float f32x4;

#define NB    16
#define DIM   256
#define NTOK  1024

__device__ __forceinline__ u16 f2b(float f) {
    union { float f; uint32_t u; } v; v.f = f;
    uint32_t u = v.u;
    u += 0x7fffu + ((u >> 16) & 1u);
    return (u16)(u >> 16);
}
__device__ __forceinline__ uint32_t pack2(float a, float b) {
    return (uint32_t)f2b(a) | ((uint32_t)f2b(b) << 16);
}
__device__ __forceinline__ f32x4 mfma16(short8 a, short8 b, f32x4 c) {
    return __builtin_amdgcn_mfma_f32_16x16x32_bf16(a, b, c, 0, 0, 0);
}
__device__ __forceinline__ f32x4 mfma_fp8(long a, long b, f32x4 c) {
    return __builtin_amdgcn_mfma_f32_16x16x32_fp8_fp8(a, b, c, 0, 0, 0);
}
__device__ __forceinline__ short8 ld8(const u16* p) {
    return *reinterpret_cast<const short8*>(p);
}
__device__ __forceinline__ uint32_t pk4fp8(float a, float b, float c, float d) {
    uint32_t u = (uint32_t)__builtin_amdgcn_cvt_pk_fp8_f32(a, b, 0, false);
    u = (uint32_t)__builtin_amdgcn_cvt_pk_fp8_f32(c, d, (int)u, true);
    return u;
}
__device__ __forceinline__ u8 pk1fp8(float a) {
    return (u8)(__builtin_amdgcn_cvt_pk_fp8_f32(a, a, 0, false) & 0xff);
}
__device__ __forceinline__ void gl_lds(const void* g, void* l) {
    __builtin_amdgcn_global_load_lds((const __attribute__((address_space(1))) void*)g,
                                     (__attribute__((address_space(3))) void*)l, 16, 0, 0);
}

// ---------------- Kernel 1: convert 3 weight matrices to bf16 (96 blocks)
__global__ __launch_bounds__(256) void wconv_kernel(const float* __restrict__ pw,
                                                    const float* __restrict__ w1,
                                                    const float* __restrict__ w2,
                                                    u16* __restrict__ wbf) {
    int e = blockIdx.x * 2048 + threadIdx.x * 8;
    const float* s; int off;
    if (e < 65536)       { s = pw; off = e; }
    else if (e < 131072) { s = w1; off = e - 65536; }
    else                 { s = w2; off = e - 131072; }
    float4 f0 = *reinterpret_cast<const float4*>(s + off);
    float4 f1 = *reinterpret_cast<const float4*>(s + off + 4);
    ushort4 a, b;
    a.x = f2b(f0.x); a.y = f2b(f0.y); a.z = f2b(f0.z); a.w = f2b(f0.w);
    b.x = f2b(f1.x); b.y = f2b(f1.y); b.z = f2b(f1.z); b.w = f2b(f1.w);
    *reinterpret_cast<ushort4*>(wbf + e)     = a;
    *reinterpret_cast<ushort4*>(wbf + e + 4) = b;
}

// ---------------- Kernel 2: fused pack + proj. Emits xbf8 (fp8 [C][N] for V)
// and qb8 (fp8 [N][C] for QK). Proj GEMM in bf16. (R19-verified.)
__global__ __launch_bounds__(256) void packproj_kernel(const float* __restrict__ x,
                                                       u8* __restrict__ xbf8,
                                                       const u16* __restrict__ wbf,
                                                       const float* __restrict__ pb,
                                                       u8* __restrict__ qb8) {
    __shared__ float stage[64][68];
    __shared__ u16 tile[64 * 256];
    int tid = threadIdx.x;
    int lane = tid & 63;
    int w = tid >> 6;
    int lo = lane & 15, hi = lane >> 4;
    int b  = blockIdx.x & 15;
    int nt = blockIdx.x >> 4;
    int n0 = nt * 64;
    const float* xb = x + (size_t)b * (DIM * NTOK);
    u8* xbb8 = xbf8 + (size_t)b * (DIM * NTOK);

#pragma unroll
    for (int cc = 0; cc < 4; cc++) {
#pragma unroll
        for (int i = 0; i < 4; i++) {
            int idx = i * 256 + tid;
            int cl = idx >> 4, nq = idx & 15;
            float4 f = *reinterpret_cast<const float4*>(
                xb + (size_t)(cc * 64 + cl) * NTOK + n0 + nq * 4);
            stage[cl][nq * 4 + 0] = f.x;
            stage[cl][nq * 4 + 1] = f.y;
            stage[cl][nq * 4 + 2] = f.z;
            stage[cl][nq * 4 + 3] = f.w;
            *reinterpret_cast<uint32_t*>(xbb8 + (size_t)(cc * 64 + cl) * NTOK + n0 + nq * 4) =
                pk4fp8(f.x, f.y, f.z, f.w);
        }
        __syncthreads();
#pragma unroll
        for (int j = 0; j < 2; j++) {
            int item = j * 256 + tid;
            int nl = item >> 3, g = item & 7;
            union { u16 s[8]; short8 v; } o;
#pragma unroll
            for (int k = 0; k < 8; k++) o.s[k] = f2b(stage[g * 8 + k][nl]);
            int gi = (cc * 8 + g) ^ (nl & 7);
            *reinterpret_cast<short8*>(&tile[nl * 256 + gi * 8]) = o.v;
        }
        __syncthreads();
    }

    f32x4 acc[16];
#pragma unroll
    for (int i = 0; i < 16; i++) acc[i] = (f32x4){0.f, 0.f, 0.f, 0.f};
    int ar = w * 16 + lo;
#pragma unroll
    for (int t = 0; t < 8; t++) {
        int gi = (t * 4 + hi) ^ (lo & 7);
        short8 a = ld8(&tile[ar * 256 + gi * 8]);
#pragma unroll
        for (int nf = 0; nf < 16; nf++) {
            short8 bfr = ld8(wbf + (nf * 16 + lo) * DIM + t * 32 + hi * 8);
            acc[nf] = mfma16(a, bfr, acc[nf]);
        }
    }
#pragma unroll
    for (int nf = 0; nf < 16; nf++) {
        int col = nf * 16 + lo;
        float bias = pb[col];
#pragma unroll
        for (int r = 0; r < 4; r++) {
            int row = n0 + w * 16 + hi * 4 + r;
            qb8[(size_t)(b * NTOK + row) * DIM + col] = pk1fp8(acc[nf][r] + bias);
        }
    }
}

// ---------------- Kernel 3: fused attention + FFN. Single kv stream (NO split,
// NO combine). 256 blocks (16 qb x 16 batch) x 256 thr; 4 waves x 16 q rows =
// 64 q rows/block; kv swept in 16 iterations of 64-row fp8 tiles (dbuf 64 KB).
// P fp8 with OFF=4 (R19-verified numerics). Separate LDS arrays (no overlays).
__global__ __launch_bounds__(256, 1) void attn_ffn_kernel(const u8* __restrict__ qb8,
                                                          const u8* __restrict__ xbf8,
                                                          const u16* __restrict__ wbf,
                                                          const float* __restrict__ b1,
                                                          const float* __restrict__ b2,
                                                          const float* __restrict__ x,
                                                          float* __restrict__ out) {
    __shared__ u8  kls[2][16384];    // [buf][64 kv rows x 256 ch fp8]  32 KB
    __shared__ u8  vls[2][16384];    // [buf][256 ch x 64 kv fp8]       32 KB
    __shared__ u8  aggts[32768];     // agg [64 q][256 ch] bf16, granule ^ (row&7)
    __shared__ u16 hl[64 * 264];     // FFN hidden tile

    int lane = threadIdx.x & 63;
    int w = threadIdx.x >> 6;            // 0..3
    int lo = lane & 15, hi = lane >> 4;
    int b  = blockIdx.x & 15;            // XCD = blk%8 = b%8
    int qt = blockIdx.x >> 4;            // 0..15
    int q0 = qt * 64 + w * 16;
    const u8* qbb = qb8  + (size_t)b * (NTOK * DIM);
    const u8* xbb = xbf8 + (size_t)b * (DIM * NTOK);
    const u16* w1b = wbf + 65536;
    const u16* w2b = wbf + 131072;

    // staging (bytes): per wave 4 K-instr (4 rows each) + 4 V-instr (16 ch each)
    int kOff[4], vOff[4], kDst[4], vDst[4];
#pragma unroll
    for (int i = 0; i < 4; i++) {
        int kr = w * 16 + i * 4 + (lane >> 4);               // K row in 64-row tile
        kOff[i] = kr * 256 + ((lane & 15) ^ (kr & 15)) * 16;
        kDst[i] = (w * 16 + i * 4) * 256;
        int vc = w * 64 + i * 16 + (lane >> 2);              // V channel
        vOff[i] = vc * 1024 + ((lane & 3) ^ (vc & 3)) * 16;  // granule ^ (ch&3)
        vDst[i] = (w * 64 + i * 16) * 64;
    }

    long bq[8];
#pragma unroll
    for (int t = 0; t < 8; t++)
        bq[t] = *reinterpret_cast<const long*>(qbb + (size_t)(q0 + lo) * 256 + t * 32 + hi * 8);

    f32x4 acc[16];
#pragma unroll
    for (int i = 0; i < 16; i++) acc[i] = (f32x4){0.f, 0.f, 0.f, 0.f};
    float ellp = 0.f;
    const float C1 = 0.0625f * 1.44269504f;
    const float OFF = 4.0f;

#pragma unroll
    for (int i = 0; i < 4; i++) {
        gl_lds(qbb + kOff[i], &kls[0][kDst[i]]);
        gl_lds(xbb + vOff[i], &vls[0][vDst[i]]);
    }
    __syncthreads();

    for (int tt = 0; tt < 16; tt++) {
        int buf = tt & 1;
        if (tt < 15) {
            int base = (tt + 1) * 64;
#pragma unroll
            for (int i = 0; i < 4; i++) {
                gl_lds(qbb + base * 256 + kOff[i], &kls[buf ^ 1][kDst[i]]);
                gl_lds(xbb + base       + vOff[i], &vls[buf ^ 1][vDst[i]]);
            }
        }
        const u8* kb = &kls[buf][0];
        const u8* vb = &vls[buf][0];

        // QK^T fp8: 4 kv-frags (rows 0..15, 16..31, 32..47, 48..63)
        f32x4 s0 = (f32x4){0.f,0.f,0.f,0.f};
        f32x4 s1 = (f32x4){0.f,0.f,0.f,0.f};
        f32x4 s2 = (f32x4){0.f,0.f,0.f,0.f};
        f32x4 s3 = (f32x4){0.f,0.f,0.f,0.f};
        __builtin_amdgcn_s_setprio(1);
#pragma unroll
        for (int t = 0; t < 8; t++) {
            int gsw = ((t * 2 + (hi >> 1)) ^ lo) * 16 + (hi & 1) * 8;
            long a0 = *reinterpret_cast<const long*>(kb + lo * 256 + gsw);
            long a1 = *reinterpret_cast<const long*>(kb + (16 + lo) * 256 + gsw);
            long a2 = *reinterpret_cast<const long*>(kb + (32 + lo) * 256 + gsw);
            long a3 = *reinterpret_cast<const long*>(kb + (48 + lo) * 256 + gsw);
            s0 = mfma_fp8(a0, bq[t], s0);
            s1 = mfma_fp8(a1, bq[t], s1);
            s2 = mfma_fp8(a2, bq[t], s2);
            s3 = mfma_fp8(a3, bq[t], s3);
        }
        __builtin_amdgcn_s_setprio(0);

        // softmax numerators, fixed OFF=4; per-lane ell
        float p0[4], p1[4], p2[4], p3[4];
#pragma unroll
        for (int r = 0; r < 4; r++) {
            p0[r] = exp2f(s0[r] * C1 - OFF);
            p1[r] = exp2f(s1[r] * C1 - OFF);
            p2[r] = exp2f(s2[r] * C1 - OFF);
            p3[r] = exp2f(s3[r] * C1 - OFF);
            ellp += (p0[r] + p1[r]) + (p2[r] + p3[r]);
        }

        // pack P to fp8, redistribute into two 32-kv B-frags (4 shfl each)
        int srcA = ((2 * hi) & 3) * 16 + lo;
        int srcB = srcA + 16;
        long pfA, pfB;
        {
            uint32_t d0 = pk4fp8(p0[0], p0[1], p0[2], p0[3]);
            uint32_t d1 = pk4fp8(p1[0], p1[1], p1[2], p1[3]);
            uint32_t a0s = __shfl(d0, srcA), a1s = __shfl(d1, srcA);
            uint32_t a0t = __shfl(d0, srcB), a1t = __shfl(d1, srcB);
            union { uint32_t u[2]; long l; } pu;
            pu.u[0] = (hi < 2) ? a0s : a1s;
            pu.u[1] = (hi < 2) ? a0t : a1t;
            pfA = pu.l;
        }
        {
            uint32_t d0 = pk4fp8(p2[0], p2[1], p2[2], p2[3]);
            uint32_t d1 = pk4fp8(p3[0], p3[1], p3[2], p3[3]);
            uint32_t a0s = __shfl(d0, srcA), a1s = __shfl(d1, srcA);
            uint32_t a0t = __shfl(d0, srcB), a1t = __shfl(d1, srcB);
            union { uint32_t u[2]; long l; } pu;
            pu.u[0] = (hi < 2) ? a0s : a1s;
            pu.u[1] = (hi < 2) ? a0t : a1t;
            pfB = pu.l;
        }

        // PV fp8: two 32-kv k-steps per channel frag
        int voffA = (((hi >> 1)    ) ^ (lo & 3)) * 16 + (hi & 1) * 8;
        int voffB = (((hi >> 1) + 2) ^ (lo & 3)) * 16 + (hi & 1) * 8;
        __builtin_amdgcn_s_setprio(1);
#pragma unroll
        for (int mf = 0; mf < 16; mf++) {
            const u8* vrow = vb + (mf * 16 + lo) * 64;
            long vfA = *reinterpret_cast<const long*>(vrow + voffA);
            long vfB = *reinterpret_cast<const long*>(vrow + voffB);
            acc[mf] = mfma_fp8(vfA, pfA, acc[mf]);
            acc[mf] = mfma_fp8(vfB, pfB, acc[mf]);
        }
        __builtin_amdgcn_s_setprio(0);
        __syncthreads();
    }

    // ---- ell reduce (wave-local, no combine) + agg tile write ----
    float e = ellp;
    e += __shfl_xor(e, 16);
    e += __shfl_xor(e, 32);
    float rinv = 1.f / e;

    char* abase = (char*)aggts;
    int arow = w * 16 + lo;
#pragma unroll
    for (int j = 0; j < 16; j++) {
        uint32_t lo32 = pack2(acc[j][0] * rinv, acc[j][1] * rinv);
        uint32_t hi32 = pack2(acc[j][2] * rinv, acc[j][3] * rinv);
        int slot = j * 2 + (hi >> 1);
        int byteA = arow * 512 + ((slot ^ (lo & 7)) * 16) + (hi & 1) * 8;
        *reinterpret_cast<uint32_t*>(abase + byteA)     = lo32;
        *reinterpret_cast<uint32_t*>(abase + byteA + 4) = hi32;
    }
    __syncthreads();

    // ---- FFN on 64 rows (R14-verified): 4 waves = 2 rowhalves x 2 colhalves ----
    int rh = w >> 1, chh = w & 1;
    f32x4 f1a[8], f1b[8];
#pragma unroll
    for (int i = 0; i < 8; i++) {
        f1a[i] = (f32x4){0.f, 0.f, 0.f, 0.f};
        f1b[i] = (f32x4){0.f, 0.f, 0.f, 0.f};
    }
#pragma unroll
    for (int t = 0; t < 8; t++) {
        int g = ((t * 4 + hi) ^ (lo & 7)) * 16;
        short8 aA = *reinterpret_cast<const short8*>(abase + (rh * 32 + lo) * 512 + g);
        short8 aB = *reinterpret_cast<const short8*>(abase + (rh * 32 + 16 + lo) * 512 + g);
#pragma unroll
        for (int nf = 0; nf < 8; nf++) {
            short8 bfr = ld8(w1b + ((chh * 8 + nf) * 16 + lo) * DIM + t * 32 + hi * 8);
            f1a[nf] = mfma16(aA, bfr, f1a[nf]);
            f1b[nf] = mfma16(aB, bfr, f1b[nf]);
        }
    }
#pragma unroll
    for (int nf = 0; nf < 8; nf++) {
        int f = (chh * 8 + nf) * 16 + lo;
        float bias = b1[f];
#pragma unroll
        for (int r = 0; r < 4; r++) {
            float va = f1a[nf][r] + bias;
            float vb2 = f1b[nf][r] + bias;
            float ga = 0.5f * va * (1.f + erff(va * 0.70710678f));
            float gb = 0.5f * vb2 * (1.f + erff(vb2 * 0.70710678f));
            hl[(rh * 32 + hi * 4 + r) * 264 + f]      = f2b(ga);
            hl[(rh * 32 + 16 + hi * 4 + r) * 264 + f] = f2b(gb);
        }
    }
    __syncthreads();

    f32x4 f2a[8], f2b_[8];
#pragma unroll
    for (int i = 0; i < 8; i++) {
        f2a[i] = (f32x4){0.f, 0.f, 0.f, 0.f};
        f2b_[i] = (f32x4){0.f, 0.f, 0.f, 0.f};
    }
#pragma unroll
    for (int t = 0; t < 8; t++) {
        short8 hA = ld8(hl + (rh * 32 + lo) * 264 + t * 32 + hi * 8);
        short8 hB = ld8(hl + (rh * 32 + 16 + lo) * 264 + t * 32 + hi * 8);
#pragma unroll
        for (int mf = 0; mf < 8; mf++) {
            short8 a2 = ld8(w2b + ((chh * 8 + mf) * 16 + lo) * DIM + t * 32 + hi * 8);
            f2a[mf] = mfma16(a2, hA, f2a[mf]);
            f2b_[mf] = mfma16(a2, hB, f2b_[mf]);
        }
    }
    int nA = qt * 64 + rh * 32 + lo;
    int nB = nA + 16;
#pragma unroll
    for (int mf = 0; mf < 8; mf++) {
#pragma unroll
        for (int r = 0; r < 4; r++) {
            int co = (chh * 8 + mf) * 16 + hi * 4 + r;
            size_t rowb = (size_t)b * (DIM * NTOK) + (size_t)co * NTOK;
            out[rowb + nA] = f2a[mf][r] + b2[co] + x[rowb + nA];
            out[rowb + nB] = f2b_[mf][r] + b2[co] + x[rowb + nB];
        }
    }
}

extern "C" void kernel_launch(void* const* d_in, const int* in_sizes, int n_in,
                              void* d_out, int out_size, void* d_ws, size_t ws_size,
                              hipStream_t stream) {
    const float* x      = (const float*)d_in[0];
    const float* proj_w = (const float*)d_in[1];
    const float* proj_b = (const float*)d_in[2];
    const float* w1     = (const float*)d_in[3];
    const float* b1     = (const float*)d_in[4];
    const float* w2     = (const float*)d_in[5];
    const float* b2     = (const float*)d_in[6];
    float* out = (float*)d_out;

    u8*  xbf8 = (u8*)d_ws;                 // 4 MB fp8 [C][N]
    u8*  qb8  = xbf8 + 4194304;            // 4 MB fp8 [N][C]
    u16* wbf  = (u16*)(qb8 + 4194304);     // 0.4 MB bf16 weights

    wconv_kernel   <<<96,  256, 0, stream>>>(proj_w, w1, w2, wbf);
    packproj_kernel<<<256, 256, 0, stream>>>(x, xbf8, wbf, proj_b, qb8);
    attn_ffn_kernel<<<256, 256, 0, stream>>>(qb8, xbf8, wbf, b1, b2, x, out);
}

// Round 21
// 97.146 us; speedup vs baseline: 1.0080x; 1.0080x over previous
//
#include <hip/hip_runtime.h>
#include <stdint.h>

typedef unsigned short u16;
typedef unsigned char u8;
typedef __attribute__((ext_vector_type(8))) short short8;
typedef __attribute__((ext_vector_type(4))) float f32x4;

#define NB    16
#define DIM   256
#define NTOK  1024

__device__ __forceinline__ u16 f2b(float f) {
    union { float f; uint32_t u; } v; v.f = f;
    uint32_t u = v.u;
    u += 0x7fffu + ((u >> 16) & 1u);
    return (u16)(u >> 16);
}
__device__ __forceinline__ uint32_t pack2(float a, float b) {
    return (uint32_t)f2b(a) | ((uint32_t)f2b(b) << 16);
}
__device__ __forceinline__ f32x4 mfma16(short8 a, short8 b, f32x4 c) {
    return __builtin_amdgcn_mfma_f32_16x16x32_bf16(a, b, c, 0, 0, 0);
}
__device__ __forceinline__ f32x4 mfma_fp8(long a, long b, f32x4 c) {
    return __builtin_amdgcn_mfma_f32_16x16x32_fp8_fp8(a, b, c, 0, 0, 0);
}
__device__ __forceinline__ short8 ld8(const u16* p) {
    return *reinterpret_cast<const short8*>(p);
}
__device__ __forceinline__ uint32_t pk4fp8(float a, float b, float c, float d) {
    uint32_t u = (uint32_t)__builtin_amdgcn_cvt_pk_fp8_f32(a, b, 0, false);
    u = (uint32_t)__builtin_amdgcn_cvt_pk_fp8_f32(c, d, (int)u, true);
    return u;
}
__device__ __forceinline__ u8 pk1fp8(float a) {
    return (u8)(__builtin_amdgcn_cvt_pk_fp8_f32(a, a, 0, false) & 0xff);
}
__device__ __forceinline__ void gl_lds(const void* g, void* l) {
    __builtin_amdgcn_global_load_lds((const __attribute__((address_space(1))) void*)g,
                                     (__attribute__((address_space(3))) void*)l, 16, 0, 0);
}

// ---------------- Kernel 1: convert 3 weight matrices to bf16 (96 blocks)
__global__ __launch_bounds__(256) void wconv_kernel(const float* __restrict__ pw,
                                                    const float* __restrict__ w1,
                                                    const float* __restrict__ w2,
                                                    u16* __restrict__ wbf) {
    int e = blockIdx.x * 2048 + threadIdx.x * 8;
    const float* s; int off;
    if (e < 65536)       { s = pw; off = e; }
    else if (e < 131072) { s = w1; off = e - 65536; }
    else                 { s = w2; off = e - 131072; }
    float4 f0 = *reinterpret_cast<const float4*>(s + off);
    float4 f1 = *reinterpret_cast<const float4*>(s + off + 4);
    ushort4 a, b;
    a.x = f2b(f0.x); a.y = f2b(f0.y); a.z = f2b(f0.z); a.w = f2b(f0.w);
    b.x = f2b(f1.x); b.y = f2b(f1.y); b.z = f2b(f1.z); b.w = f2b(f1.w);
    *reinterpret_cast<ushort4*>(wbf + e)     = a;
    *reinterpret_cast<ushort4*>(wbf + e + 4) = b;
}

// ---------------- Kernel 2: fused pack + proj (R19-verified).
__global__ __launch_bounds__(256) void packproj_kernel(const float* __restrict__ x,
                                                       u8* __restrict__ xbf8,
                                                       const u16* __restrict__ wbf,
                                                       const float* __restrict__ pb,
                                                       u8* __restrict__ qb8) {
    __shared__ float stage[64][68];
    __shared__ u16 tile[64 * 256];
    int tid = threadIdx.x;
    int lane = tid & 63;
    int w = tid >> 6;
    int lo = lane & 15, hi = lane >> 4;
    int b  = blockIdx.x & 15;
    int nt = blockIdx.x >> 4;
    int n0 = nt * 64;
    const float* xb = x + (size_t)b * (DIM * NTOK);
    u8* xbb8 = xbf8 + (size_t)b * (DIM * NTOK);

#pragma unroll
    for (int cc = 0; cc < 4; cc++) {
#pragma unroll
        for (int i = 0; i < 4; i++) {
            int idx = i * 256 + tid;
            int cl = idx >> 4, nq = idx & 15;
            float4 f = *reinterpret_cast<const float4*>(
                xb + (size_t)(cc * 64 + cl) * NTOK + n0 + nq * 4);
            stage[cl][nq * 4 + 0] = f.x;
            stage[cl][nq * 4 + 1] = f.y;
            stage[cl][nq * 4 + 2] = f.z;
            stage[cl][nq * 4 + 3] = f.w;
            *reinterpret_cast<uint32_t*>(xbb8 + (size_t)(cc * 64 + cl) * NTOK + n0 + nq * 4) =
                pk4fp8(f.x, f.y, f.z, f.w);
        }
        __syncthreads();
#pragma unroll
        for (int j = 0; j < 2; j++) {
            int item = j * 256 + tid;
            int nl = item >> 3, g = item & 7;
            union { u16 s[8]; short8 v; } o;
#pragma unroll
            for (int k = 0; k < 8; k++) o.s[k] = f2b(stage[g * 8 + k][nl]);
            int gi = (cc * 8 + g) ^ (nl & 7);
            *reinterpret_cast<short8*>(&tile[nl * 256 + gi * 8]) = o.v;
        }
        __syncthreads();
    }

    f32x4 acc[16];
#pragma unroll
    for (int i = 0; i < 16; i++) acc[i] = (f32x4){0.f, 0.f, 0.f, 0.f};
    int ar = w * 16 + lo;
#pragma unroll
    for (int t = 0; t < 8; t++) {
        int gi = (t * 4 + hi) ^ (lo & 7);
        short8 a = ld8(&tile[ar * 256 + gi * 8]);
#pragma unroll
        for (int nf = 0; nf < 16; nf++) {
            short8 bfr = ld8(wbf + (nf * 16 + lo) * DIM + t * 32 + hi * 8);
            acc[nf] = mfma16(a, bfr, acc[nf]);
        }
    }
#pragma unroll
    for (int nf = 0; nf < 16; nf++) {
        int col = nf * 16 + lo;
        float bias = pb[col];
#pragma unroll
        for (int r = 0; r < 4; r++) {
            int row = n0 + w * 16 + hi * 4 + r;
            qb8[(size_t)(b * NTOK + row) * DIM + col] = pk1fp8(acc[nf][r] + bias);
        }
    }
}

// ---------------- Kernel 3: fused attention + FFN (R20 body) with T3/T4 sync:
// counted s_waitcnt vmcnt(8) + raw s_barrier, stage issued depth-2 ahead.
// Never drains vmcnt to 0 in the main loop (the __syncthreads drain was the wall).
__global__ __launch_bounds__(256, 1) void attn_ffn_kernel(const u8* __restrict__ qb8,
                                                          const u8* __restrict__ xbf8,
                                                          const u16* __restrict__ wbf,
                                                          const float* __restrict__ b1,
                                                          const float* __restrict__ b2,
                                                          const float* __restrict__ x,
                                                          float* __restrict__ out) {
    __shared__ u8  kls[2][16384];    // [buf][64 kv rows x 256 ch fp8]  32 KB
    __shared__ u8  vls[2][16384];    // [buf][256 ch x 64 kv fp8]       32 KB
    __shared__ u8  aggts[32768];     // agg [64 q][256 ch] bf16, granule ^ (row&7)
    __shared__ u16 hl[64 * 264];     // FFN hidden tile

    int lane = threadIdx.x & 63;
    int w = threadIdx.x >> 6;            // 0..3
    int lo = lane & 15, hi = lane >> 4;
    int b  = blockIdx.x & 15;            // XCD = blk%8 = b%8
    int qt = blockIdx.x >> 4;            // 0..15
    int q0 = qt * 64 + w * 16;
    const u8* qbb = qb8  + (size_t)b * (NTOK * DIM);
    const u8* xbb = xbf8 + (size_t)b * (DIM * NTOK);
    const u16* w1b = wbf + 65536;
    const u16* w2b = wbf + 131072;

    // staging (bytes): per wave 4 K-instr (4 rows each) + 4 V-instr (16 ch each)
    int kOff[4], vOff[4], kDst[4], vDst[4];
#pragma unroll
    for (int i = 0; i < 4; i++) {
        int kr = w * 16 + i * 4 + (lane >> 4);
        kOff[i] = kr * 256 + ((lane & 15) ^ (kr & 15)) * 16;
        kDst[i] = (w * 16 + i * 4) * 256;
        int vc = w * 64 + i * 16 + (lane >> 2);
        vOff[i] = vc * 1024 + ((lane & 3) ^ (vc & 3)) * 16;
        vDst[i] = (w * 64 + i * 16) * 64;
    }

    long bq[8];
#pragma unroll
    for (int t = 0; t < 8; t++)
        bq[t] = *reinterpret_cast<const long*>(qbb + (size_t)(q0 + lo) * 256 + t * 32 + hi * 8);
    // drain bq so in-loop vmcnt counts ONLY staging loads (8 per wave per tile)
    asm volatile("s_waitcnt vmcnt(0)" ::: "memory");

    f32x4 acc[16];
#pragma unroll
    for (int i = 0; i < 16; i++) acc[i] = (f32x4){0.f, 0.f, 0.f, 0.f};
    float ellp = 0.f;
    const float C1 = 0.0625f * 1.44269504f;
    const float OFF = 4.0f;

    // prologue: stage tiles 0 and 1 (16 loads outstanding)
#pragma unroll
    for (int i = 0; i < 4; i++) {
        gl_lds(qbb + kOff[i], &kls[0][kDst[i]]);
        gl_lds(xbb + vOff[i], &vls[0][vDst[i]]);
    }
#pragma unroll
    for (int i = 0; i < 4; i++) {
        gl_lds(qbb + 64 * 256 + kOff[i], &kls[1][kDst[i]]);
        gl_lds(xbb + 64       + vOff[i], &vls[1][vDst[i]]);
    }

    for (int tt = 0; tt < 16; tt++) {
        int buf = tt & 1;
        // wait: tile tt landed (its 8 loads are the oldest); tile tt+1 stays in flight
        if (tt < 15) asm volatile("s_waitcnt vmcnt(8)" ::: "memory");
        else         asm volatile("s_waitcnt vmcnt(0)" ::: "memory");
        __builtin_amdgcn_s_barrier();

        const u8* kb = &kls[buf][0];
        const u8* vb = &vls[buf][0];

        // QK^T fp8: 4 kv-frags (rows 0..15, 16..31, 32..47, 48..63)
        f32x4 s0 = (f32x4){0.f,0.f,0.f,0.f};
        f32x4 s1 = (f32x4){0.f,0.f,0.f,0.f};
        f32x4 s2 = (f32x4){0.f,0.f,0.f,0.f};
        f32x4 s3 = (f32x4){0.f,0.f,0.f,0.f};
        __builtin_amdgcn_s_setprio(1);
#pragma unroll
        for (int t = 0; t < 8; t++) {
            int gsw = ((t * 2 + (hi >> 1)) ^ lo) * 16 + (hi & 1) * 8;
            long a0 = *reinterpret_cast<const long*>(kb + lo * 256 + gsw);
            long a1 = *reinterpret_cast<const long*>(kb + (16 + lo) * 256 + gsw);
            long a2 = *reinterpret_cast<const long*>(kb + (32 + lo) * 256 + gsw);
            long a3 = *reinterpret_cast<const long*>(kb + (48 + lo) * 256 + gsw);
            s0 = mfma_fp8(a0, bq[t], s0);
            s1 = mfma_fp8(a1, bq[t], s1);
            s2 = mfma_fp8(a2, bq[t], s2);
            s3 = mfma_fp8(a3, bq[t], s3);
        }
        __builtin_amdgcn_s_setprio(0);

        // softmax numerators, fixed OFF=4; per-lane ell
        float p0[4], p1[4], p2[4], p3[4];
#pragma unroll
        for (int r = 0; r < 4; r++) {
            p0[r] = exp2f(s0[r] * C1 - OFF);
            p1[r] = exp2f(s1[r] * C1 - OFF);
            p2[r] = exp2f(s2[r] * C1 - OFF);
            p3[r] = exp2f(s3[r] * C1 - OFF);
            ellp += (p0[r] + p1[r]) + (p2[r] + p3[r]);
        }

        // pack P to fp8, redistribute into two 32-kv B-frags (4 shfl each)
        int srcA = ((2 * hi) & 3) * 16 + lo;
        int srcB = srcA + 16;
        long pfA, pfB;
        {
            uint32_t d0 = pk4fp8(p0[0], p0[1], p0[2], p0[3]);
            uint32_t d1 = pk4fp8(p1[0], p1[1], p1[2], p1[3]);
            uint32_t a0s = __shfl(d0, srcA), a1s = __shfl(d1, srcA);
            uint32_t a0t = __shfl(d0, srcB), a1t = __shfl(d1, srcB);
            union { uint32_t u[2]; long l; } pu;
            pu.u[0] = (hi < 2) ? a0s : a1s;
            pu.u[1] = (hi < 2) ? a0t : a1t;
            pfA = pu.l;
        }
        {
            uint32_t d0 = pk4fp8(p2[0], p2[1], p2[2], p2[3]);
            uint32_t d1 = pk4fp8(p3[0], p3[1], p3[2], p3[3]);
            uint32_t a0s = __shfl(d0, srcA), a1s = __shfl(d1, srcA);
            uint32_t a0t = __shfl(d0, srcB), a1t = __shfl(d1, srcB);
            union { uint32_t u[2]; long l; } pu;
            pu.u[0] = (hi < 2) ? a0s : a1s;
            pu.u[1] = (hi < 2) ? a0t : a1t;
            pfB = pu.l;
        }

        // PV fp8: two 32-kv k-steps per channel frag
        int voffA = (((hi >> 1)    ) ^ (lo & 3)) * 16 + (hi & 1) * 8;
        int voffB = (((hi >> 1) + 2) ^ (lo & 3)) * 16 + (hi & 1) * 8;
        __builtin_amdgcn_s_setprio(1);
#pragma unroll
        for (int mf = 0; mf < 16; mf++) {
            const u8* vrow = vb + (mf * 16 + lo) * 64;
            long vfA = *reinterpret_cast<const long*>(vrow + voffA);
            long vfB = *reinterpret_cast<const long*>(vrow + voffB);
            acc[mf] = mfma_fp8(vfA, pfA, acc[mf]);
            acc[mf] = mfma_fp8(vfB, pfB, acc[mf]);
        }
        __builtin_amdgcn_s_setprio(0);

        // all waves done READING buf before anyone overwrites it
        __builtin_amdgcn_s_barrier();
        if (tt + 2 <= 15) {
            int base = (tt + 2) * 64;
#pragma unroll
            for (int i = 0; i < 4; i++) {
                gl_lds(qbb + base * 256 + kOff[i], &kls[buf][kDst[i]]);
                gl_lds(xbb + base       + vOff[i], &vls[buf][vDst[i]]);
            }
        }
    }

    // ---- ell reduce (wave-local) + agg tile write ----
    float e = ellp;
    e += __shfl_xor(e, 16);
    e += __shfl_xor(e, 32);
    float rinv = 1.f / e;

    char* abase = (char*)aggts;
    int arow = w * 16 + lo;
#pragma unroll
    for (int j = 0; j < 16; j++) {
        uint32_t lo32 = pack2(acc[j][0] * rinv, acc[j][1] * rinv);
        uint32_t hi32 = pack2(acc[j][2] * rinv, acc[j][3] * rinv);
        int slot = j * 2 + (hi >> 1);
        int byteA = arow * 512 + ((slot ^ (lo & 7)) * 16) + (hi & 1) * 8;
        *reinterpret_cast<uint32_t*>(abase + byteA)     = lo32;
        *reinterpret_cast<uint32_t*>(abase + byteA + 4) = hi32;
    }
    __syncthreads();

    // ---- FFN on 64 rows (R14-verified): 4 waves = 2 rowhalves x 2 colhalves ----
    int rh = w >> 1, chh = w & 1;
    f32x4 f1a[8], f1b[8];
#pragma unroll
    for (int i = 0; i < 8; i++) {
        f1a[i] = (f32x4){0.f, 0.f, 0.f, 0.f};
        f1b[i] = (f32x4){0.f, 0.f, 0.f, 0.f};
    }
#pragma unroll
    for (int t = 0; t < 8; t++) {
        int g = ((t * 4 + hi) ^ (lo & 7)) * 16;
        short8 aA = *reinterpret_cast<const short8*>(abase + (rh * 32 + lo) * 512 + g);
        short8 aB = *reinterpret_cast<const short8*>(abase + (rh * 32 + 16 + lo) * 512 + g);
#pragma unroll
        for (int nf = 0; nf < 8; nf++) {
            short8 bfr = ld8(w1b + ((chh * 8 + nf) * 16 + lo) * DIM + t * 32 + hi * 8);
            f1a[nf] = mfma16(aA, bfr, f1a[nf]);
            f1b[nf] = mfma16(aB, bfr, f1b[nf]);
        }
    }
#pragma unroll
    for (int nf = 0; nf < 8; nf++) {
        int f = (chh * 8 + nf) * 16 + lo;
        float bias = b1[f];
#pragma unroll
        for (int r = 0; r < 4; r++) {
            float va = f1a[nf][r] + bias;
            float vb2 = f1b[nf][r] + bias;
            float ga = 0.5f * va * (1.f + erff(va * 0.70710678f));
            float gb = 0.5f * vb2 * (1.f + erff(vb2 * 0.70710678f));
            hl[(rh * 32 + hi * 4 + r) * 264 + f]      = f2b(ga);
            hl[(rh * 32 + 16 + hi * 4 + r) * 264 + f] = f2b(gb);
        }
    }
    __syncthreads();

    f32x4 f2a[8], f2b_[8];
#pragma unroll
    for (int i = 0; i < 8; i++) {
        f2a[i] = (f32x4){0.f, 0.f, 0.f, 0.f};
        f2b_[i] = (f32x4){0.f, 0.f, 0.f, 0.f};
    }
#pragma unroll
    for (int t = 0; t < 8; t++) {
        short8 hA = ld8(hl + (rh * 32 + lo) * 264 + t * 32 + hi * 8);
        short8 hB = ld8(hl + (rh * 32 + 16 + lo) * 264 + t * 32 + hi * 8);
#pragma unroll
        for (int mf = 0; mf < 8; mf++) {
            short8 a2 = ld8(w2b + ((chh * 8 + mf) * 16 + lo) * DIM + t * 32 + hi * 8);
            f2a[mf] = mfma16(a2, hA, f2a[mf]);
            f2b_[mf] = mfma16(a2, hB, f2b_[mf]);
        }
    }
    int nA = qt * 64 + rh * 32 + lo;
    int nB = nA + 16;
#pragma unroll
    for (int mf = 0; mf < 8; mf++) {
#pragma unroll
        for (int r = 0; r < 4; r++) {
            int co = (chh * 8 + mf) * 16 + hi * 4 + r;
            size_t rowb = (size_t)b * (DIM * NTOK) + (size_t)co * NTOK;
            out[rowb + nA] = f2a[mf][r] + b2[co] + x[rowb + nA];
            out[rowb + nB] = f2b_[mf][r] + b2[co] + x[rowb + nB];
        }
    }
}

extern "C" void kernel_launch(void* const* d_in, const int* in_sizes, int n_in,
                              void* d_out, int out_size, void* d_ws, size_t ws_size,
                              hipStream_t stream) {
    const float* x      = (const float*)d_in[0];
    const float* proj_w = (const float*)d_in[1];
    const float* proj_b = (const float*)d_in[2];
    const float* w1     = (const float*)d_in[3];
    const float* b1     = (const float*)d_in[4];
    const float* w2     = (const float*)d_in[5];
    const float* b2     = (const float*)d_in[6];
    float* out = (float*)d_out;

    u8*  xbf8 = (u8*)d_ws;                 // 4 MB fp8 [C][N]
    u8*  qb8  = xbf8 + 4194304;            // 4 MB fp8 [N][C]
    u16* wbf  = (u16*)(qb8 + 4194304);     // 0.4 MB bf16 weights

    wconv_kernel   <<<96,  256, 0, stream>>>(proj_w, w1, w2, wbf);
    packproj_kernel<<<256, 256, 0, stream>>>(x, xbf8, wbf, proj_b, qb8);
    attn_ffn_kernel<<<256, 256, 0, stream>>>(qb8, xbf8, wbf, b1, b2, x, out);
}